// Round 7
// baseline (185.274 us; speedup 1.0000x reference)
//
#include <hip/hip_runtime.h>

// Problem constants (from reference setup_inputs)
#define BB 2
#define CC 16
#define TT 8
#define HH 64
#define WW 64
#define CO 16
#define KK 27          // 3*3*3 taps
#define THW (TT*HH*WW) // 32768
#define HW  (HH*WW)    // 4096

typedef _Float16 h8   __attribute__((ext_vector_type(8)));   // 16 B
typedef _Float16 h16  __attribute__((ext_vector_type(16)));  // 32 B
typedef float    f32x2 __attribute__((ext_vector_type(2)));

#define NROW 13        // tile rows [h0-5, h0+7]  (covers |off| <= 4)
#define ROWB 2048      // bytes per staged row: 64 cols * 16 ch * 2 B

// ---------------------------------------------------------------------------
// Prep: blocks [0,256): x [B,C,T,H,W] -> xT [B,T,H,W,C] fp16 (32 B/pos)
//       blocks [256,283): weight [Co,C,3,3,3] -> wT [k][c][co] fp32
// ---------------------------------------------------------------------------
__global__ __launch_bounds__(256) void prep(const float* __restrict__ x,
                                            const float* __restrict__ w,
                                            _Float16* __restrict__ xT,
                                            float* __restrict__ wT) {
    int bid = blockIdx.x;
    if (bid < 256) {
        int pos = bid * 256 + threadIdx.x;          // B*T*H*W = 65536
        int b = pos / THW;
        int s = pos - b * THW;
        h16 hv;
#pragma unroll
        for (int c = 0; c < CC; ++c)
            hv[c] = (_Float16)x[(size_t)(b * CC + c) * THW + s];
        *(h16*)(xT + (size_t)pos * CC) = hv;
    } else {
        int id = (bid - 256) * 256 + threadIdx.x;   // 27*256 = 6912
        if (id < KK * CC * CO) {
            int k  = id / (CC * CO);
            int c  = (id / CO) % CC;
            int co = id % CO;
            wT[id] = w[(size_t)(co * CC + c) * KK + k];
        }
    }
}

// XOR swizzle: spread bank-group bits a[6:4] with c[4:2] ^ rr[1:0] so a
// wave's scattered 16B reads cover ~8 bank groups instead of 4-of-32 banks.
// Bijective within each 128B span; identical on write and read side.
__device__ __forceinline__ int swz(int rr, int c, int base) {
    int sw = ((((c >> 2) ^ rr) & 3) << 4) | (((c >> 4) & 1) << 6);
    return base ^ sw;
}

// ---------------------------------------------------------------------------
// Main: 128 threads = 2 output rows x 64 w. Stage 3 t-planes x 13 h-rows of
// fp16 channel-last x into LDS (78 KB, 2 blocks/CU); bilinear gathers hit
// LDS (swizzled ds_read_b128); |off|>4 lanes take a rare global fallback.
// Interp in packed fp16, 16x16 contraction in f32x2 (wave-uniform weights).
// ---------------------------------------------------------------------------
__global__ __launch_bounds__(128) void deform_lds(
    const _Float16* __restrict__ xT, const float* __restrict__ temp,
    const float* __restrict__ wT, const float* __restrict__ bias,
    float* __restrict__ out)
{
    __shared__ char lds[3 * NROW * ROWB];           // 79872 B

    int tid = threadIdx.x;
    int blk = blockIdx.x;                           // 512 = B*T*(H/2)
    int b   = blk >> 8;
    int rem = blk & 255;
    int t   = rem >> 5;
    int h0  = (rem & 31) * 2;
    int rlo = max(0, h0 - 5);
    int rhi = min(HH - 1, h0 + 7);

    // ---- stage tile: one (plane,row) 2 KB segment per iteration ----
    {
        int c  = tid >> 1;
        int hh = tid & 1;
#pragma unroll
        for (int i = 0; i < 3 * NROW; ++i) {
            int kt = i / NROW, rr = i - kt * NROW;
            int pt = t - 1 + kt;
            int r  = rlo + rr;
            if (pt < 0 || pt >= TT || r > rhi) continue;   // block-uniform
            const h8* src = (const h8*)(xT +
                ((size_t)((b * TT + pt) * HW + r * WW + c) * CC) + hh * 8);
            int base = i * ROWB + c * 32 + hh * 16;
            *(h8*)(lds + swz(rr, c, base)) = *src;
        }
    }
    __syncthreads();

    int h = h0 + (tid >> 6);                        // uniform per wave
    int w = tid & 63;
    int s = t * HW + h * WW + w;
    const float* tb = temp + (size_t)b * (2 * KK) * THW + s;

    f32x2 acc2[8];
    const f32x2* b2 = (const f32x2*)bias;
#pragma unroll
    for (int j = 0; j < 8; ++j) acc2[j] = b2[j];

#pragma unroll
    for (int kt = 0; kt < 3; ++kt) {
        int pt = t - 1 + kt;                        // offset_t == 0 exactly
        if (pt < 0 || pt >= TT) continue;           // block-uniform

        // preload this plane's 9 taps' offsets (18 independent loads)
        float offh[9], offw[9];
#pragma unroll
        for (int j = 0; j < 9; ++j) {
            int k = kt * 9 + j;
            offh[j] = tb[(size_t)(2 * k)     * THW];
            offw[j] = tb[(size_t)(2 * k + 1) * THW];
        }

#pragma unroll
        for (int j = 0; j < 9; ++j) {
            int kh = j / 3, kw = j - kh * 3;
            float ph = (float)(h - 1 + kh) + offh[j];
            float pw = (float)(w - 1 + kw) + offw[j];
            float r0f = floorf(ph), w0f = floorf(pw);
            float fh = ph - r0f, fw = pw - w0f;
            int r0 = (int)r0f, w0i = (int)w0f;
            int r1 = r0 + 1, w1i = w0i + 1;
            bool vh0 = (unsigned)r0  < (unsigned)HH;
            bool vh1 = (unsigned)r1  < (unsigned)HH;
            bool vw0 = (unsigned)w0i < (unsigned)WW;
            bool vw1 = (unsigned)w1i < (unsigned)WW;
            float fh1 = 1.f - fh, fw1 = 1.f - fw;
            float c00 = fh1 * fw1 * ((vh0 && vw0) ? 1.f : 0.f);
            float c01 = fh1 * fw  * ((vh0 && vw1) ? 1.f : 0.f);
            float c10 = fh  * fw1 * ((vh1 && vw0) ? 1.f : 0.f);
            float c11 = fh  * fw  * ((vh1 && vw1) ? 1.f : 0.f);
            int c0 = min(max(w0i, 0), WW - 1);
            int c1 = min(max(w1i, 0), WW - 1);
            int rr0 = min(max(r0, rlo), rhi) - rlo;
            int rr1 = min(max(r1, rlo), rhi) - rlo;
            int pb = kt * (NROW * ROWB);

            h8 q00a = *(const h8*)(lds + swz(rr0, c0, pb + rr0 * ROWB + c0 * 32));
            h8 q00b = *(const h8*)(lds + swz(rr0, c0, pb + rr0 * ROWB + c0 * 32 + 16));
            h8 q01a = *(const h8*)(lds + swz(rr0, c1, pb + rr0 * ROWB + c1 * 32));
            h8 q01b = *(const h8*)(lds + swz(rr0, c1, pb + rr0 * ROWB + c1 * 32 + 16));
            h8 q10a = *(const h8*)(lds + swz(rr1, c0, pb + rr1 * ROWB + c0 * 32));
            h8 q10b = *(const h8*)(lds + swz(rr1, c0, pb + rr1 * ROWB + c0 * 32 + 16));
            h8 q11a = *(const h8*)(lds + swz(rr1, c1, pb + rr1 * ROWB + c1 * 32));
            h8 q11b = *(const h8*)(lds + swz(rr1, c1, pb + rr1 * ROWB + c1 * 32 + 16));

            // rare |off|>4 fallback: valid sample row outside staged tile
            bool ob0 = vh0 && (r0 < rlo || r0 > rhi);
            bool ob1 = vh1 && (r1 < rlo || r1 > rhi);
            if (__builtin_expect(__any(ob0 || ob1), 0)) {
                const h8* xg = (const h8*)(xT +
                    (size_t)((b * TT + pt) * HW) * CC);
                if (ob0) {
                    q00a = xg[(r0 * WW + c0) * 2];
                    q00b = xg[(r0 * WW + c0) * 2 + 1];
                    q01a = xg[(r0 * WW + c1) * 2];
                    q01b = xg[(r0 * WW + c1) * 2 + 1];
                }
                if (ob1) {
                    q10a = xg[(r1 * WW + c0) * 2];
                    q10b = xg[(r1 * WW + c0) * 2 + 1];
                    q11a = xg[(r1 * WW + c1) * 2];
                    q11b = xg[(r1 * WW + c1) * 2 + 1];
                }
            }

            // packed fp16 bilinear interp
            _Float16 h00 = (_Float16)c00, h01 = (_Float16)c01;
            _Float16 h10 = (_Float16)c10, h11 = (_Float16)c11;
            h8 va = q00a * h00 + q01a * h01 + q10a * h10 + q11a * h11;
            h8 vb = q00b * h00 + q01b * h01 + q10b * h10 + q11b * h11;

            // contraction: acc[co] += val[c] * W[k][c][co], f32x2 packed
            const f32x2* wk = (const f32x2*)(wT + (kt * 9 + j) * (CC * CO));
#pragma unroll
            for (int c = 0; c < CC; ++c) {
                float vc = (float)((c < 8) ? va[c] : vb[c - 8]);
#pragma unroll
                for (int jj = 0; jj < 8; ++jj)
                    acc2[jj] += wk[c * 8 + jj] * vc;
            }
        }
    }

    float* op = out + (size_t)b * CO * THW + s;
#pragma unroll
    for (int j = 0; j < 8; ++j) {
        op[(size_t)(2 * j)     * THW] = acc2[j][0];
        op[(size_t)(2 * j + 1) * THW] = acc2[j][1];
    }
}

// ---------------------------------------------------------------------------
// Safety fallback if workspace is too small: direct fp32 global-gather.
// ---------------------------------------------------------------------------
__global__ __launch_bounds__(256) void deform_global(
    const float* __restrict__ x, const float* __restrict__ temp,
    const float* __restrict__ weight, const float* __restrict__ bias,
    float* __restrict__ out)
{
    int pos = blockIdx.x * 256 + threadIdx.x;
    int b = pos / THW, s = pos - b * THW;
    int t = s / HW, hw = s - t * HW, h = hw >> 6, w = hw & 63;
    float acc[CO];
#pragma unroll
    for (int co = 0; co < CO; ++co) acc[co] = bias[co];
#pragma unroll 1
    for (int k = 0; k < KK; ++k) {
        int kt = k / 9, kh = (k / 3) % 3, kw = k % 3;
        int pt = t - 1 + kt;
        if (pt < 0 || pt >= TT) continue;
        const float* tb = temp + (size_t)b * (2 * KK) * THW + s;
        float ph = (float)(h - 1 + kh) + tb[(size_t)(2 * k) * THW];
        float pw = (float)(w - 1 + kw) + tb[(size_t)(2 * k + 1) * THW];
        float h0f = floorf(ph), w0f = floorf(pw);
        float fh = ph - h0f, fw = pw - w0f;
        int h0 = (int)h0f, w0 = (int)w0f;
        float val[CC];
#pragma unroll
        for (int c = 0; c < CC; ++c) val[c] = 0.f;
#pragma unroll
        for (int dh = 0; dh < 2; ++dh) {
            int hi = h0 + dh;
            float whf = dh ? fh : (1.f - fh);
            bool vh = (hi >= 0) && (hi < HH);
            int hic = min(max(hi, 0), HH - 1);
#pragma unroll
            for (int dw_ = 0; dw_ < 2; ++dw_) {
                int wi = w0 + dw_;
                float wwf = dw_ ? fw : (1.f - fw);
                bool vw = (wi >= 0) && (wi < WW);
                int wic = min(max(wi, 0), WW - 1);
                float coef = whf * wwf * ((vh && vw) ? 1.f : 0.f);
                const float* xp = x + (size_t)(b * CC) * THW + pt * HW
                                + hic * WW + wic;
#pragma unroll
                for (int c = 0; c < CC; ++c)
                    val[c] = fmaf(coef, xp[(size_t)c * THW], val[c]);
            }
        }
#pragma unroll
        for (int c = 0; c < CC; ++c)
#pragma unroll
            for (int co = 0; co < CO; ++co)
                acc[co] = fmaf(val[c], weight[(size_t)(co * CC + c) * KK + k],
                               acc[co]);
    }
#pragma unroll
    for (int co = 0; co < CO; ++co)
        out[(size_t)(b * CO + co) * THW + s] = acc[co];
}

// ---------------------------------------------------------------------------
extern "C" void kernel_launch(void* const* d_in, const int* in_sizes, int n_in,
                              void* d_out, int out_size, void* d_ws, size_t ws_size,
                              hipStream_t stream) {
    const float* x      = (const float*)d_in[0];
    const float* temp   = (const float*)d_in[1];
    const float* weight = (const float*)d_in[2];
    const float* bias   = (const float*)d_in[3];
    float* out = (float*)d_out;

    const size_t xT_bytes = (size_t)BB * THW * CC * sizeof(_Float16); // 2 MiB
    const size_t wT_bytes = (size_t)KK * CC * CO * sizeof(float);     // 27 KiB

    if (ws_size >= xT_bytes + wT_bytes) {
        _Float16* xT = (_Float16*)d_ws;
        float*    wT = (float*)((char*)d_ws + xT_bytes);
        hipLaunchKernelGGL(prep, dim3(256 + 27), dim3(256), 0, stream,
                           x, weight, xT, wT);
        hipLaunchKernelGGL(deform_lds, dim3(BB * TT * (HH / 2)), dim3(128),
                           0, stream, xT, temp, wT, bias, out);
    } else {
        hipLaunchKernelGGL(deform_global, dim3((BB * THW) / 256), dim3(256),
                           0, stream, x, temp, weight, bias, out);
    }
}

// Round 8
// 97.804 us; speedup vs baseline: 1.8943x; 1.8943x over previous
//
#include <hip/hip_runtime.h>

// Problem constants (from reference setup_inputs)
#define BB 2
#define CC 16
#define TT 8
#define HH 64
#define WW 64
#define CO 16
#define KK 27          // 3*3*3 taps
#define THW (TT*HH*WW) // 32768
#define HW  (HH*WW)    // 4096

typedef _Float16 h8   __attribute__((ext_vector_type(8)));   // 16 B
typedef _Float16 h16  __attribute__((ext_vector_type(16)));  // 32 B
typedef int      i4   __attribute__((ext_vector_type(4)));
typedef float    f32x2 __attribute__((ext_vector_type(2)));

// ---------------------------------------------------------------------------
// Prep: blocks [0,256): x [B,C,T,H,W] -> xT [B,T,H,W,C] fp16 (32 B/pos)
//       blocks [256,283): weight [Co,C,3,3,3] -> wT [k][c][co] fp32
// ---------------------------------------------------------------------------
__global__ __launch_bounds__(256) void prep(const float* __restrict__ x,
                                            const float* __restrict__ w,
                                            _Float16* __restrict__ xT,
                                            float* __restrict__ wT) {
    int bid = blockIdx.x;
    if (bid < 256) {
        int pos = bid * 256 + threadIdx.x;          // B*T*H*W = 65536
        int b = pos / THW;
        int s = pos - b * THW;
        h16 hv;
#pragma unroll
        for (int c = 0; c < CC; ++c)
            hv[c] = (_Float16)x[(size_t)(b * CC + c) * THW + s];
        *(h16*)(xT + (size_t)pos * CC) = hv;
    } else {
        int id = (bid - 256) * 256 + threadIdx.x;   // 27*256 = 6912
        if (id < KK * CC * CO) {
            int k  = id / (CC * CO);
            int c  = (id / CO) % CC;
            int co = id % CO;
            wT[id] = w[(size_t)(co * CC + c) * KK + k];
        }
    }
}

// DPP quad_perm broadcast within lane-pairs:
//   CTRL 0xA0 = [0,0,2,2] : both lanes of a pair get the EVEN lane's value
//   CTRL 0xF5 = [1,1,3,3] : both lanes of a pair get the ODD lane's value
template <int CTRL>
__device__ __forceinline__ h8 dppq(h8 v) {
    i4 sv = __builtin_bit_cast(i4, v);
    i4 d;
#pragma unroll
    for (int j = 0; j < 4; ++j)
        d[j] = __builtin_amdgcn_mov_dpp(sv[j], CTRL, 0xF, 0xF, true);
    return __builtin_bit_cast(h8, d);
}

// ---------------------------------------------------------------------------
// Main: 512 threads = 64 positions x 2 channel-halves x 4 tap-groups.
// Lane pair (2m,2m+1) loads the same position's low/high 8 fp16 channels
// (adjacent 16B -> shared 64B line: ~2x fewer TA line-requests than R5).
// DPP quad_perm recombines halves in-register; contraction keeps
// wave-uniform s_load weights. Tap-groups reduced via 16 KB LDS.
// ---------------------------------------------------------------------------
__global__ __launch_bounds__(512, 4) void deform_pair(
    const _Float16* __restrict__ xT, const float* __restrict__ temp,
    const float* __restrict__ wT, const float* __restrict__ bias,
    float* __restrict__ out)
{
    __shared__ float red[4 * CO * 64];              // 16 KiB

    int tid = threadIdx.x;
    int e   = tid & 1;                              // channel half
    int wl  = (tid >> 1) & 31;
    int wh  = __builtin_amdgcn_readfirstlane((tid >> 6) & 1);
    int g   = __builtin_amdgcn_readfirstlane(tid >> 7);   // tap group 0..3
    int w   = wh * 32 + wl;                         // position 0..63
    int s0  = blockIdx.x * 64;
    int b   = s0 / THW;
    int sb  = s0 - b * THW;                         // t*HW + h*64 (uniform)
    int t   = sb / HW;
    int h   = (sb - t * HW) >> 6;

    // ---- preload this group's offsets (pair lanes load same addr) ----
    const float* tb = temp + (size_t)b * (2 * KK) * THW + sb + w;
    float offh[7], offw[7];
#pragma unroll
    for (int i = 0; i < 7; ++i) {
        int k = g + 4 * i;
        if (k < KK) {
            offh[i] = tb[(size_t)(2 * k)     * THW];
            offw[i] = tb[(size_t)(2 * k + 1) * THW];
        }
    }

    f32x2 acc2[8];
#pragma unroll
    for (int j = 0; j < 8; ++j) acc2[j] = f32x2{0.f, 0.f};

#pragma unroll
    for (int i = 0; i < 7; ++i) {
        int k = g + 4 * i;
        if (k >= KK) continue;                      // wave-uniform
        int kt = k / 9, kh = (k / 3) % 3, kw = k % 3;
        int pt = t - 1 + kt;                        // offset_t == 0 exactly
        if (pt < 0 || pt >= TT) continue;           // wave-uniform

        float ph = (float)(h - 1 + kh) + offh[i];
        float pw = (float)(w - 1 + kw) + offw[i];
        float r0f = floorf(ph), w0f = floorf(pw);
        float fh = ph - r0f, fw = pw - w0f;
        int r0 = (int)r0f, w0i = (int)w0f;
        int r1 = r0 + 1, w1i = w0i + 1;
        bool vh0 = (unsigned)r0  < (unsigned)HH;
        bool vh1 = (unsigned)r1  < (unsigned)HH;
        bool vw0 = (unsigned)w0i < (unsigned)WW;
        bool vw1 = (unsigned)w1i < (unsigned)WW;
        float fh1 = 1.f - fh, fw1 = 1.f - fw;
        float c00 = fh1 * fw1 * ((vh0 && vw0) ? 1.f : 0.f);
        float c01 = fh1 * fw  * ((vh0 && vw1) ? 1.f : 0.f);
        float c10 = fh  * fw1 * ((vh1 && vw0) ? 1.f : 0.f);
        float c11 = fh  * fw  * ((vh1 && vw1) ? 1.f : 0.f);
        int cc0 = min(max(w0i, 0), WW - 1);
        int cc1 = min(max(w1i, 0), WW - 1);
        int rr0 = min(max(r0, 0), HH - 1);
        int rr1 = min(max(r1, 0), HH - 1);

        // per-lane 16B loads: pair lanes cover adjacent halves of one 32B pos
        const _Float16* xb = xT + (size_t)((b * TT + pt) * HW) * CC + e * 8;
        h8 q00 = *(const h8*)(xb + (size_t)(rr0 * WW + cc0) * CC);
        h8 q01 = *(const h8*)(xb + (size_t)(rr0 * WW + cc1) * CC);
        h8 q10 = *(const h8*)(xb + (size_t)(rr1 * WW + cc0) * CC);
        h8 q11 = *(const h8*)(xb + (size_t)(rr1 * WW + cc1) * CC);

        // packed fp16 bilinear interp on this lane's 8 channels
        h8 va = q00 * (_Float16)c00 + q01 * (_Float16)c01
              + q10 * (_Float16)c10 + q11 * (_Float16)c11;

        // recombine halves in-register via DPP pair-broadcast
        h8 vlow  = dppq<0xA0>(va);                  // ch 0..7  (even lane's)
        h8 vhigh = dppq<0xF5>(va);                  // ch 8..15 (odd lane's)

        // contraction: acc[co] += val[c] * W[k][c][co]; weights wave-uniform
        const f32x2* wk = (const f32x2*)(wT + k * (CC * CO));
#pragma unroll
        for (int c = 0; c < 8; ++c) {
            float vl = (float)vlow[c];
            float vh = (float)vhigh[c];
#pragma unroll
            for (int jj = 0; jj < 8; ++jj) {
                acc2[jj] += wk[c * 8 + jj] * vl;
                acc2[jj] += wk[(c + 8) * 8 + jj] * vh;
            }
        }
    }

    // ---- cross-group reduction via LDS (pair lanes hold identical acc) ----
    if (e == 0) {
#pragma unroll
        for (int j = 0; j < 8; ++j) {
            red[g * (CO * 64) + (2 * j)     * 64 + w] = acc2[j][0];
            red[g * (CO * 64) + (2 * j + 1) * 64 + w] = acc2[j][1];
        }
    }
    __syncthreads();

#pragma unroll
    for (int rep = 0; rep < 2; ++rep) {
        int idx = tid + rep * 512;                  // 1024 (co,pos) outputs
        int co = idx >> 6, pp = idx & 63;
        float sum = red[             co * 64 + pp]
                  + red[1 * CO * 64 + co * 64 + pp]
                  + red[2 * CO * 64 + co * 64 + pp]
                  + red[3 * CO * 64 + co * 64 + pp] + bias[co];
        out[(size_t)b * CO * THW + (size_t)co * THW + sb + pp] = sum;
    }
}

// ---------------------------------------------------------------------------
// Safety fallback if workspace is too small: direct fp32 global-gather.
// ---------------------------------------------------------------------------
__global__ __launch_bounds__(256) void deform_global(
    const float* __restrict__ x, const float* __restrict__ temp,
    const float* __restrict__ weight, const float* __restrict__ bias,
    float* __restrict__ out)
{
    int pos = blockIdx.x * 256 + threadIdx.x;
    int b = pos / THW, s = pos - b * THW;
    int t = s / HW, hw = s - t * HW, h = hw >> 6, w = hw & 63;
    float acc[CO];
#pragma unroll
    for (int co = 0; co < CO; ++co) acc[co] = bias[co];
#pragma unroll 1
    for (int k = 0; k < KK; ++k) {
        int kt = k / 9, kh = (k / 3) % 3, kw = k % 3;
        int pt = t - 1 + kt;
        if (pt < 0 || pt >= TT) continue;
        const float* tb = temp + (size_t)b * (2 * KK) * THW + s;
        float ph = (float)(h - 1 + kh) + tb[(size_t)(2 * k) * THW];
        float pw = (float)(w - 1 + kw) + tb[(size_t)(2 * k + 1) * THW];
        float h0f = floorf(ph), w0f = floorf(pw);
        float fh = ph - h0f, fw = pw - w0f;
        int h0 = (int)h0f, w0 = (int)w0f;
        float val[CC];
#pragma unroll
        for (int c = 0; c < CC; ++c) val[c] = 0.f;
#pragma unroll
        for (int dh = 0; dh < 2; ++dh) {
            int hi = h0 + dh;
            float whf = dh ? fh : (1.f - fh);
            bool vh = (hi >= 0) && (hi < HH);
            int hic = min(max(hi, 0), HH - 1);
#pragma unroll
            for (int dw_ = 0; dw_ < 2; ++dw_) {
                int wi = w0 + dw_;
                float wwf = dw_ ? fw : (1.f - fw);
                bool vw = (wi >= 0) && (wi < WW);
                int wic = min(max(wi, 0), WW - 1);
                float coef = whf * wwf * ((vh && vw) ? 1.f : 0.f);
                const float* xp = x + (size_t)(b * CC) * THW + pt * HW
                                + hic * WW + wic;
#pragma unroll
                for (int c = 0; c < CC; ++c)
                    val[c] = fmaf(coef, xp[(size_t)c * THW], val[c]);
            }
        }
#pragma unroll
        for (int c = 0; c < CC; ++c)
#pragma unroll
            for (int co = 0; co < CO; ++co)
                acc[co] = fmaf(val[c], weight[(size_t)(co * CC + c) * KK + k],
                               acc[co]);
    }
#pragma unroll
    for (int co = 0; co < CO; ++co)
        out[(size_t)(b * CO + co) * THW + s] = acc[co];
}

// ---------------------------------------------------------------------------
extern "C" void kernel_launch(void* const* d_in, const int* in_sizes, int n_in,
                              void* d_out, int out_size, void* d_ws, size_t ws_size,
                              hipStream_t stream) {
    const float* x      = (const float*)d_in[0];
    const float* temp   = (const float*)d_in[1];
    const float* weight = (const float*)d_in[2];
    const float* bias   = (const float*)d_in[3];
    float* out = (float*)d_out;

    const size_t xT_bytes = (size_t)BB * THW * CC * sizeof(_Float16); // 2 MiB
    const size_t wT_bytes = (size_t)KK * CC * CO * sizeof(float);     // 27 KiB

    if (ws_size >= xT_bytes + wT_bytes) {
        _Float16* xT = (_Float16*)d_ws;
        float*    wT = (float*)((char*)d_ws + xT_bytes);
        hipLaunchKernelGGL(prep, dim3(256 + 27), dim3(256), 0, stream,
                           x, weight, xT, wT);
        hipLaunchKernelGGL(deform_pair, dim3((BB * THW) / 64), dim3(512),
                           0, stream, xT, temp, wT, bias, out);
    } else {
        hipLaunchKernelGGL(deform_global, dim3((BB * THW) / 256), dim3(256),
                           0, stream, x, temp, weight, bias, out);
    }
}

// Round 10
// 91.200 us; speedup vs baseline: 2.0315x; 1.0724x over previous
//
#include <hip/hip_runtime.h>

// Problem constants (from reference setup_inputs)
#define BB 2
#define CC 16
#define TT 8
#define HH 64
#define WW 64
#define CO 16
#define KK 27          // 3*3*3 taps
#define THW (TT*HH*WW) // 32768
#define HW  (HH*WW)    // 4096

typedef _Float16 h8   __attribute__((ext_vector_type(8)));   // 16 B
typedef _Float16 h16  __attribute__((ext_vector_type(16)));  // 32 B
typedef float    f32x2 __attribute__((ext_vector_type(2)));

#define NROW 13        // tile rows [h0-5, h0+7]  (covers |off| <= 4)
#define ROWB 2048      // bytes per staged row: 64 cols * 16 ch * 2 B
#define TILEB (3 * NROW * ROWB)   // 79872 B

// ---------------------------------------------------------------------------
// Prep: blocks [0,256): x [B,C,T,H,W] -> xT [B,T,H,W,C] fp16 (32 B/pos)
//       blocks [256,283): weight [Co,C,3,3,3] -> wT [k][c][co] fp32
// ---------------------------------------------------------------------------
__global__ __launch_bounds__(256) void prep(const float* __restrict__ x,
                                            const float* __restrict__ w,
                                            _Float16* __restrict__ xT,
                                            float* __restrict__ wT) {
    int bid = blockIdx.x;
    if (bid < 256) {
        int pos = bid * 256 + threadIdx.x;          // B*T*H*W = 65536
        int b = pos / THW;
        int s = pos - b * THW;
        h16 hv;
#pragma unroll
        for (int c = 0; c < CC; ++c)
            hv[c] = (_Float16)x[(size_t)(b * CC + c) * THW + s];
        *(h16*)(xT + (size_t)pos * CC) = hv;
    } else {
        int id = (bid - 256) * 256 + threadIdx.x;   // 27*256 = 6912
        if (id < KK * CC * CO) {
            int k  = id / (CC * CO);
            int c  = (id / CO) % CC;
            int co = id % CO;
            wT[id] = w[(size_t)(co * CC + c) * KK + k];
        }
    }
}

// XOR swizzle: spread bank-group bits a[6:4] with c[4:2]^rr[1:0] and c[4] so
// a wave's scattered 16B reads cover all 8 bank groups. Bijective (XOR of
// low bits with bits that live higher in the address); SAME function applied
// on write and read side. Proven correct+effective in R7 (absmax 0.0156,
// conflicts 1.3M cy).
__device__ __forceinline__ int swz(int rr, int c, int base) {
    int sw = ((((c >> 2) ^ rr) & 3) << 4) | (((c >> 4) & 1) << 6);
    return base ^ sw;
}

// ---------------------------------------------------------------------------
// Main: 512 threads = 8 waves = 2 output rows x 4 tap-groups; 64 pos/wave.
// Stage 3 t-planes x 13 h-rows of fp16 channel-last x into 78 KB LDS
// (cooperatively, all 8 waves); gathers are swizzled ds_read_b128; rare
// |off|>4 samples fall back to global. Tap-group partials reduced by
// reusing the staging LDS. 2 blocks/CU (156 KB LDS, VGPR capped 128)
// -> 16 waves/CU, vs R7's 3 waves/CU (its failure mode).
// ---------------------------------------------------------------------------
__global__ __launch_bounds__(512, 4) void deform_lds2(
    const _Float16* __restrict__ xT, const float* __restrict__ temp,
    const float* __restrict__ wT, const float* __restrict__ bias,
    float* __restrict__ out)
{
    __shared__ __align__(16) char lds[TILEB];       // 79872 B

    int tid = threadIdx.x;
    int lane = tid & 63;
    int wid  = __builtin_amdgcn_readfirstlane(tid >> 6);   // 0..7
    int row  = wid >> 2;                            // output row 0/1
    int g    = wid & 3;                             // tap group 0..3
    int blk = blockIdx.x;                           // 512 = B*T*(H/2)
    int b   = blk >> 8;
    int rem = blk & 255;
    int t   = rem >> 5;
    int h0  = (rem & 31) * 2;
    int rlo = max(0, h0 - 5);
    int rhi = min(HH - 1, h0 + 7);

    int h = h0 + row;
    int w = lane;
    const float* tb = temp + (size_t)b * (2 * KK) * THW
                    + (size_t)t * HW + h * WW + w;

    // ---- issue this wave's tap offsets FIRST (latency hides under staging)
    float offh[7], offw[7];
#pragma unroll
    for (int i = 0; i < 7; ++i) {
        int k = g + 4 * i;
        if (k < KK) {
            offh[i] = tb[(size_t)(2 * k)     * THW];
            offw[i] = tb[(size_t)(2 * k + 1) * THW];
        }
    }

    // ---- cooperative staging: 4992 coalesced 16B chunks over 512 threads
    {
        const int nchunk = 3 * NROW * 128;          // 4992
#pragma unroll
        for (int it = 0; it < 10; ++it) {
            int chunk = tid + it * 512;
            if (chunk >= nchunk) break;
            int kt  = chunk / (NROW * 128);
            int r2  = chunk - kt * (NROW * 128);
            int rr  = r2 >> 7;
            int j   = r2 & 127;                     // 16B chunk in row
            int pt  = t - 1 + kt;
            int r   = rlo + rr;
            if (pt >= 0 && pt < TT && r <= rhi) {
                const h8* src = (const h8*)(xT +
                    (size_t)((b * TT + pt) * HW + r * WW) * CC) + j;
                int dst = kt * (NROW * ROWB) + rr * ROWB + j * 16;
                *(h8*)(lds + swz(rr, j >> 1, dst)) = *src;
            }
        }
    }
    __syncthreads();

    f32x2 acc2[8];
#pragma unroll
    for (int j = 0; j < 8; ++j) acc2[j] = f32x2{0.f, 0.f};

#pragma unroll
    for (int i = 0; i < 7; ++i) {
        int k = g + 4 * i;
        if (k >= KK) continue;                      // wave-uniform
        int kt = k / 9, kh = (k / 3) % 3, kw = k % 3;
        int pt = t - 1 + kt;                        // offset_t == 0 exactly
        if (pt < 0 || pt >= TT) continue;           // block-uniform

        float ph = (float)(h - 1 + kh) + offh[i];
        float pw = (float)(w - 1 + kw) + offw[i];
        float r0f = floorf(ph), w0f = floorf(pw);
        float fh = ph - r0f, fw = pw - w0f;
        int r0 = (int)r0f, w0i = (int)w0f;
        int r1 = r0 + 1, w1i = w0i + 1;
        bool vh0 = (unsigned)r0  < (unsigned)HH;
        bool vh1 = (unsigned)r1  < (unsigned)HH;
        bool vw0 = (unsigned)w0i < (unsigned)WW;
        bool vw1 = (unsigned)w1i < (unsigned)WW;
        float fh1 = 1.f - fh, fw1 = 1.f - fw;
        float c00 = fh1 * fw1 * ((vh0 && vw0) ? 1.f : 0.f);
        float c01 = fh1 * fw  * ((vh0 && vw1) ? 1.f : 0.f);
        float c10 = fh  * fw1 * ((vh1 && vw0) ? 1.f : 0.f);
        float c11 = fh  * fw  * ((vh1 && vw1) ? 1.f : 0.f);
        int cc0 = min(max(w0i, 0), WW - 1);
        int cc1 = min(max(w1i, 0), WW - 1);
        int rr0 = min(max(r0, rlo), rhi) - rlo;
        int rr1 = min(max(r1, rlo), rhi) - rlo;
        int pb = kt * (NROW * ROWB);

        h8 q00a = *(const h8*)(lds + swz(rr0, cc0, pb + rr0 * ROWB + cc0 * 32));
        h8 q00b = *(const h8*)(lds + swz(rr0, cc0, pb + rr0 * ROWB + cc0 * 32 + 16));
        h8 q01a = *(const h8*)(lds + swz(rr0, cc1, pb + rr0 * ROWB + cc1 * 32));
        h8 q01b = *(const h8*)(lds + swz(rr0, cc1, pb + rr0 * ROWB + cc1 * 32 + 16));
        h8 q10a = *(const h8*)(lds + swz(rr1, cc0, pb + rr1 * ROWB + cc0 * 32));
        h8 q10b = *(const h8*)(lds + swz(rr1, cc0, pb + rr1 * ROWB + cc0 * 32 + 16));
        h8 q11a = *(const h8*)(lds + swz(rr1, cc1, pb + rr1 * ROWB + cc1 * 32));
        h8 q11b = *(const h8*)(lds + swz(rr1, cc1, pb + rr1 * ROWB + cc1 * 32 + 16));

        // rare |off|>4 fallback: valid sample row outside staged tile
        bool ob0 = vh0 && (r0 < rlo || r0 > rhi);
        bool ob1 = vh1 && (r1 < rlo || r1 > rhi);
        if (__builtin_expect(__any(ob0 || ob1), 0)) {
            const h8* xg = (const h8*)(xT + (size_t)((b * TT + pt) * HW) * CC);
            if (ob0) {
                q00a = xg[(r0 * WW + cc0) * 2];
                q00b = xg[(r0 * WW + cc0) * 2 + 1];
                q01a = xg[(r0 * WW + cc1) * 2];
                q01b = xg[(r0 * WW + cc1) * 2 + 1];
            }
            if (ob1) {
                q10a = xg[(r1 * WW + cc0) * 2];
                q10b = xg[(r1 * WW + cc0) * 2 + 1];
                q11a = xg[(r1 * WW + cc1) * 2];
                q11b = xg[(r1 * WW + cc1) * 2 + 1];
            }
        }

        // packed fp16 bilinear interp
        _Float16 h00 = (_Float16)c00, h01 = (_Float16)c01;
        _Float16 h10 = (_Float16)c10, h11 = (_Float16)c11;
        h8 va = q00a * h00 + q01a * h01 + q10a * h10 + q11a * h11;
        h8 vb = q00b * h00 + q01b * h01 + q10b * h10 + q11b * h11;

        // contraction: acc[co] += val[c] * W[k][c][co] (weights -> s_load)
        const f32x2* wk = (const f32x2*)(wT + k * (CC * CO));
#pragma unroll
        for (int c = 0; c < 8; ++c) {
            float vl = (float)va[c];
            float vh = (float)vb[c];
#pragma unroll
            for (int jj = 0; jj < 8; ++jj) {
                acc2[jj] += wk[c * 8 + jj] * vl;
                acc2[jj] += wk[(c + 8) * 8 + jj] * vh;
            }
        }
    }

    // ---- cross-group reduction: reuse staging LDS (32 KB of it) ----
    __syncthreads();                                // all tap reads done
    float* red = (float*)lds;                       // [row][g][co][pos]
#pragma unroll
    for (int jj = 0; jj < 8; ++jj) {
        red[((row * 4 + g) * CO + 2 * jj)     * 64 + w] = acc2[jj][0];
        red[((row * 4 + g) * CO + 2 * jj + 1) * 64 + w] = acc2[jj][1];
    }
    __syncthreads();

#pragma unroll
    for (int it = 0; it < 4; ++it) {
        int idx = tid + it * 512;                   // 2048 (row,co,pos) outs
        int row2 = idx >> 10;
        int co   = (idx >> 6) & 15;
        int p    = idx & 63;
        float sum = bias[co];
#pragma unroll
        for (int gg = 0; gg < 4; ++gg)
            sum += red[((row2 * 4 + gg) * CO + co) * 64 + p];
        out[(size_t)b * CO * THW + (size_t)co * THW
            + t * HW + (h0 + row2) * WW + p] = sum;
    }
}

// ---------------------------------------------------------------------------
// Safety fallback if workspace is too small: direct fp32 global-gather.
// ---------------------------------------------------------------------------
__global__ __launch_bounds__(256) void deform_global(
    const float* __restrict__ x, const float* __restrict__ temp,
    const float* __restrict__ weight, const float* __restrict__ bias,
    float* __restrict__ out)
{
    int pos = blockIdx.x * 256 + threadIdx.x;
    int b = pos / THW, s = pos - b * THW;
    int t = s / HW, hw = s - t * HW, h = hw >> 6, w = hw & 63;
    float acc[CO];
#pragma unroll
    for (int co = 0; co < CO; ++co) acc[co] = bias[co];
#pragma unroll 1
    for (int k = 0; k < KK; ++k) {
        int kt = k / 9, kh = (k / 3) % 3, kw = k % 3;
        int pt = t - 1 + kt;
        if (pt < 0 || pt >= TT) continue;
        const float* tb = temp + (size_t)b * (2 * KK) * THW + s;
        float ph = (float)(h - 1 + kh) + tb[(size_t)(2 * k) * THW];
        float pw = (float)(w - 1 + kw) + tb[(size_t)(2 * k + 1) * THW];
        float h0f = floorf(ph), w0f = floorf(pw);
        float fh = ph - h0f, fw = pw - w0f;
        int h0 = (int)h0f, w0 = (int)w0f;
        float val[CC];
#pragma unroll
        for (int c = 0; c < CC; ++c) val[c] = 0.f;
#pragma unroll
        for (int dh = 0; dh < 2; ++dh) {
            int hi = h0 + dh;
            float whf = dh ? fh : (1.f - fh);
            bool vh = (hi >= 0) && (hi < HH);
            int hic = min(max(hi, 0), HH - 1);
#pragma unroll
            for (int dw_ = 0; dw_ < 2; ++dw_) {
                int wi = w0 + dw_;
                float wwf = dw_ ? fw : (1.f - fw);
                bool vw = (wi >= 0) && (wi < WW);
                int wic = min(max(wi, 0), WW - 1);
                float coef = whf * wwf * ((vh && vw) ? 1.f : 0.f);
                const float* xp = x + (size_t)(b * CC) * THW + pt * HW
                                + hic * WW + wic;
#pragma unroll
                for (int c = 0; c < CC; ++c)
                    val[c] = fmaf(coef, xp[(size_t)c * THW], val[c]);
            }
        }
#pragma unroll
        for (int c = 0; c < CC; ++c)
#pragma unroll
            for (int co = 0; co < CO; ++co)
                acc[co] = fmaf(val[c], weight[(size_t)(co * CC + c) * KK + k],
                               acc[co]);
    }
#pragma unroll
    for (int co = 0; co < CO; ++co)
        out[(size_t)(b * CO + co) * THW + s] = acc[co];
}

// ---------------------------------------------------------------------------
extern "C" void kernel_launch(void* const* d_in, const int* in_sizes, int n_in,
                              void* d_out, int out_size, void* d_ws, size_t ws_size,
                              hipStream_t stream) {
    const float* x      = (const float*)d_in[0];
    const float* temp   = (const float*)d_in[1];
    const float* weight = (const float*)d_in[2];
    const float* bias   = (const float*)d_in[3];
    float* out = (float*)d_out;

    const size_t xT_bytes = (size_t)BB * THW * CC * sizeof(_Float16); // 2 MiB
    const size_t wT_bytes = (size_t)KK * CC * CO * sizeof(float);     // 27 KiB

    if (ws_size >= xT_bytes + wT_bytes) {
        _Float16* xT = (_Float16*)d_ws;
        float*    wT = (float*)((char*)d_ws + xT_bytes);
        hipLaunchKernelGGL(prep, dim3(256 + 27), dim3(256), 0, stream,
                           x, weight, xT, wT);
        hipLaunchKernelGGL(deform_lds2, dim3(BB * TT * (HH / 2)), dim3(512),
                           0, stream, xT, temp, wT, bias, out);
    } else {
        hipLaunchKernelGGL(deform_global, dim3((BB * THW) / 256), dim3(256),
                           0, stream, x, temp, weight, bias, out);
    }
}